// Round 7
// baseline (362.533 us; speedup 1.0000x reference)
//
#include <hip/hip_runtime.h>

typedef unsigned int u32;
typedef unsigned short u16;
typedef float f32x4 __attribute__((ext_vector_type(4)));
typedef u32 u32x4 __attribute__((ext_vector_type(4)));
typedef short s16x8 __attribute__((ext_vector_type(8)));

__device__ __forceinline__ u32 f2bf(float f) {
  u32 x = __builtin_bit_cast(u32, f);
  return (x + 0x7FFFu + ((x >> 16) & 1u)) >> 16;   // RNE f32 -> bf16 bits
}
__device__ __forceinline__ float bfu2f(u16 u) {
  u32 x = ((u32)u) << 16;
  return __builtin_bit_cast(float, x);
}
__device__ __forceinline__ u32 cvtpk(float lo, float hi) {
  u32 r;
  asm("v_cvt_pk_bf16_f32 %0, %1, %2" : "=v"(r) : "v"(lo), "v"(hi));
  return r;
}
__device__ __forceinline__ u32x4 mk8(const float* v) {
  u32x4 u;
  u.x = cvtpk(v[0], v[1]); u.y = cvtpk(v[2], v[3]);
  u.z = cvtpk(v[4], v[5]); u.w = cvtpk(v[6], v[7]);
  return u;
}
// D = A*B + D, 16x16x32 bf16 builtin. D: n=lane&15, m=(lane>>4)*4+r.
__device__ __forceinline__ void mfma16(f32x4& acc, u32x4 a, u32x4 b) {
  acc = __builtin_amdgcn_mfma_f32_16x16x32_bf16(
      __builtin_bit_cast(s16x8, a), __builtin_bit_cast(s16x8, b), acc, 0, 0, 0);
}

// ---------------------------------------------------------------------------
// K0 (R6-proven verbatim body): gather x into phi1[p][s][f][b], f: [x,1-x].
// Block 0 additionally zeroes the 192-float BN accumulator block.
// ---------------------------------------------------------------------------
__global__ __launch_bounds__(256) void k_gather1(const float* __restrict__ x,
                                                 float* __restrict__ phi1,
                                                 float* __restrict__ sumsAll) {
  __shared__ float tile[64][65];
  const int t = threadIdx.x;
  if (blockIdx.x == 0 && t < 192) sumsAll[t] = 0.f;
  const int base = blockIdx.x * 64;
  const int lb = t & 63;
  {
    const int flat = base + lb;
    const int c = flat >> 14;
    const int r1 = flat & 16383;
    const int h1 = r1 >> 12;
    const int r2 = r1 & 4095;
    const int w1 = r2 >> 10;
    const int r3 = r2 & 1023;
    const int h2 = r3 >> 5;
    const int w2 = r3 & 31;
    const int xoff = c * 16384 + h1 * 4096 + h2 * 128 + w1 * 32 + w2;
    for (int b = t >> 6; b < 64; b += 4)
      tile[lb][b] = x[b * 49152 + xoff];
  }
  __syncthreads();
  for (int q = t >> 6; q < 64; q += 4) {
    const int flat = base + q;
    const int a = flat / 1536;
    const int rem = flat % 1536;
    const int e = rem / 48, gg = rem % 48;
    const int e1 = e >> 4, e2 = e & 15, g1 = gg >> 4, g2 = gg & 15;
    const int tt = a * 6 + e1 * 3 + g1;
    const int F = tt >> 2, Sx = tt & 3, Pp = e2 * 16 + g2;
    const float val = tile[q][lb];
    const int idx = ((Pp * 4 + Sx) * 96 + F) * 64 + lb;
    phi1[idx] = val;
    phi1[idx + 3072] = 1.0f - val;   // f+48
  }
}

// ---------------------------------------------------------------------------
// K1 (R6-proven verbatim body + BN1 atomic tail): level-1 fused vector-chain.
// ---------------------------------------------------------------------------
__global__ __launch_bounds__(512) void k_level1(const float* __restrict__ phi1,
                                                const float* __restrict__ cores1,
                                                const float* __restrict__ label1,
                                                float* __restrict__ y1raw,
                                                float* __restrict__ sums1) {
  __shared__ float phi_s[96 * 64];          // 24 KB
  __shared__ float v_s[64 * 33];            // 8.4 KB
  __shared__ float red_s[8 * 4 * 16 * 17];  // 34.8 KB
  __shared__ float lab_s[1024];             // 4 KB
  const int p = blockIdx.x, t = threadIdx.x;
  const int w = t >> 6, lane = t & 63, g = lane >> 4, l15 = lane & 15;
  const int jm = w & 1, fq = w >> 1;
  const float* phip = phi1 + p * 24576;
  const float* Cp = cores1 + p * 393216;

  // stage phi(site 0)
  {
    const float4* s4 = (const float4*)phip;
    float4* d4 = (float4*)phi_s;
#pragma unroll
    for (int k = 0; k < 3; ++k) d4[t + k * 512] = s4[t + k * 512];
  }
  __syncthreads();
  // site 0: v[b,j] = sum_f phi[b,f] * C[p,0,f,0,j]
  {
    const int rowj = jm * 16 + l15, colb = fq * 16 + l15;
    f32x4 acc = {0.f, 0.f, 0.f, 0.f};
    const float* A0 = Cp + rowj;
#pragma unroll
    for (int ks = 0; ks < 3; ++ks) {
      float av[8], bv[8];
#pragma unroll
      for (int e = 0; e < 8; ++e) {
        const int f = ks * 32 + g * 8 + e;
        av[e] = A0[f * 1024];
        bv[e] = phi_s[f * 64 + colb];
      }
      mfma16(acc, mk8(av), mk8(bv));
    }
#pragma unroll
    for (int r = 0; r < 4; ++r) v_s[colb * 33 + jm * 16 + g * 4 + r] = acc[r];
  }
  // sites 1..3
  for (int s = 1; s < 4; ++s) {
    __syncthreads();   // v_s complete; phi_s free
    float v8[4][8];
#pragma unroll
    for (int n = 0; n < 4; ++n)
#pragma unroll
      for (int e = 0; e < 8; ++e)
        v8[n][e] = v_s[(n * 16 + l15) * 33 + g * 8 + e];
    {
      const float4* s4 = (const float4*)(phip + s * 6144);
      float4* d4 = (float4*)phi_s;
#pragma unroll
      for (int k = 0; k < 3; ++k) d4[t + k * 512] = s4[t + k * 512];
    }
    // A(f,e) = As[f*1024 + e*32] = C[p][s][fq*24+f][i=g*8+e][j=jm*16+l15]
    const float* As = Cp + s * 98304 + fq * 24576 + g * 256 + jm * 16 + l15;
    float pf[6][8];
#pragma unroll
    for (int fi = 0; fi < 6; ++fi)
#pragma unroll
      for (int e = 0; e < 8; ++e) pf[fi][e] = As[fi * 1024 + e * 32];
    __syncthreads();   // phi ready
    f32x4 acc[4];
#pragma unroll
    for (int n = 0; n < 4; ++n) acc[n] = (f32x4){0.f, 0.f, 0.f, 0.f};
#pragma unroll
    for (int fo = 0; fo < 4; ++fo) {
#pragma unroll
      for (int fi = 0; fi < 6; ++fi) {
        const int f = fo * 6 + fi;
        const u32x4 afr = mk8(pf[fi]);
        if (f + 6 < 24) {
#pragma unroll
          for (int e = 0; e < 8; ++e) pf[fi][e] = As[(f + 6) * 1024 + e * 32];
        }
#pragma unroll
        for (int n = 0; n < 4; ++n) {
          const float phf = phi_s[(fq * 24 + f) * 64 + n * 16 + l15];
          float bv[8];
#pragma unroll
          for (int e = 0; e < 8; ++e) bv[e] = phf * v8[n][e];
          mfma16(acc[n], afr, mk8(bv));
        }
      }
    }
#pragma unroll
    for (int n = 0; n < 4; ++n)
#pragma unroll
      for (int r = 0; r < 4; ++r)
        red_s[((w * 4 + n) * 16 + g * 4 + r) * 17 + l15] = acc[n][r];
    __syncthreads();
    // v[b][j] = sum of 4 fq-partials (waves jj+2*fq)
    for (int i = t; i < 2048; i += 512) {
      const int b = i >> 5, j = i & 31;
      const int n = b >> 4, lb = b & 15, jj = j >> 4, row = j & 15;
      v_s[b * 33 + j] = red_s[(((jj)*4 + n) * 16 + row) * 17 + lb]
                      + red_s[(((jj + 2) * 4 + n) * 16 + row) * 17 + lb]
                      + red_s[(((jj + 4) * 4 + n) * 16 + row) * 17 + lb]
                      + red_s[(((jj + 6) * 4 + n) * 16 + row) * 17 + lb];
    }
  }
  __syncthreads();
  // label contraction: y[b,o] = sum_j v[b,j] * label1[p,o,j,0]
  for (int i = t; i < 1024; i += 512)
    lab_s[(i & 31) * 32 + (i >> 5)] = label1[(p * 1024 + i) * 32];
  __syncthreads();
  {
    const int b = t & 63, og = t >> 6;
    float a[4] = {0.f, 0.f, 0.f, 0.f};
    for (int j = 0; j < 32; ++j) {
      const float vj = v_s[b * 33 + j];
#pragma unroll
      for (int r = 0; r < 4; ++r) a[r] += vj * lab_s[j * 32 + og * 4 + r];
    }
#pragma unroll
    for (int r = 0; r < 4; ++r)
      y1raw[((og * 4 + r) * 256 + p) * 64 + b] = a[r];
    // BN1 partial stats: wave og owns channels og*4+r
#pragma unroll
    for (int r = 0; r < 4; ++r) {
      float sr = a[r], qr = a[r] * a[r];
#pragma unroll
      for (int off = 32; off > 0; off >>= 1) {
        sr += __shfl_xor(sr, off, 64);
        qr += __shfl_xor(qr, off, 64);
      }
      if (lane == 0) {
        atomicAdd(&sums1[2 * (og * 4 + r)], sr);
        atomicAdd(&sums1[2 * (og * 4 + r) + 1], qr);
      }
    }
  }
}

// ---------------------------------------------------------------------------
// Build site matrices (levels 2,3, final). BN scale/shift derived in-block
// from fused sums. s==0 blocks (one per p) also prepack the chain label
// slice densely (levels 2,3).
// ---------------------------------------------------------------------------
template <int LEVEL>
__global__ __launch_bounds__(512) void k_build(const float* __restrict__ yraw,
                                               const float* __restrict__ cores,
                                               u16* __restrict__ mats,
                                               float* __restrict__ v0,
                                               const float* __restrict__ sums,
                                               const float* __restrict__ gamma,
                                               const float* __restrict__ beta,
                                               const float* __restrict__ label,
                                               float* __restrict__ labD) {
  constexpr int S = (LEVEL == 0) ? 16 : 4;
  constexpr int NQ = (LEVEL == 2) ? 2 : ((LEVEL == 3) ? 4 : 16);
  constexpr int NC = 1024 / NQ;
  constexpr int NTW = NC / 32;
  constexpr float BN_N = (LEVEL == 2) ? 16384.f : ((LEVEL == 3) ? 4096.f : 1024.f);
  __shared__ float phi_s[64 * 64];
  __shared__ float scsh_s[64];
  const int bid = blockIdx.x;
  const int p = bid / (S * NQ);
  const int rs = bid % (S * NQ);
  const int s = rs / NQ, nq = rs % NQ;
  if (s == 0 && nq != 0) return;   // block-uniform early exit
  const int t = threadIdx.x;
  const int w = t >> 6, lane = t & 63;
  const int g = lane >> 4, l15 = lane & 15;
  if (t < 32) {
    const float sm = sums[2 * t], sq = sums[2 * t + 1];
    const float mean = sm / BN_N;
    const float var = sq / BN_N - mean * mean;
    const float sc = gamma[t] * rsqrtf(fmaxf(var, 0.f) + 1e-5f);
    scsh_s[2 * t] = sc;
    scsh_s[2 * t + 1] = beta[t] - mean * sc;
  }
  if constexpr (LEVEL != 0) {
    if (s == 0) {   // one block per p: dense label prepack [j*32+o]
      for (int i = t; i < 1024; i += 512)
        labD[p * 1024 + ((i & 31) * 32 + (i >> 5))] = label[(p * 1024 + i) * 32];
    }
  }
  __syncthreads();   // scsh_s ready
  for (int i = t; i < 2048; i += 512) {
    const int f = i >> 6, b = i & 63;
    int src;
    if (LEVEL == 2) {
      const int u = (s >> 1) * 8 + (p >> 3), vv = (s & 1) * 8 + (p & 7);
      src = (f * 256 + u * 16 + vv) * 64 + b;
    } else if (LEVEL == 3) {
      const int u = (s >> 1) * 4 + (p >> 2), vv = (s & 1) * 4 + (p & 3);
      src = (f * 64 + u * 8 + vv) * 64 + b;
    } else {
      src = (f * 16 + s) * 64 + b;
    }
    const float val = fmaf(yraw[src], scsh_s[2 * f], scsh_s[2 * f + 1]);
    phi_s[f * 64 + b] = val;
    phi_s[(f + 32) * 64 + b] = 1.0f - val;
  }
  __syncthreads();
  const float* Cb = cores + (p * S + s) * 65536;
  const int m = w & 3, nh = w >> 2;
  const int rowb = m * 16 + l15;
  float av[8];
#pragma unroll
  for (int e = 0; e < 8; ++e) av[e] = phi_s[(g * 8 + e) * 64 + rowb];
  const u32x4 afr0 = mk8(av);
#pragma unroll
  for (int e = 0; e < 8; ++e) av[e] = phi_s[(32 + g * 8 + e) * 64 + rowb];
  const u32x4 afr1 = mk8(av);
  if (s == 0) {
    const int col = nh * 16 + l15;   // j in [0,32)
    f32x4 acc = {0.f, 0.f, 0.f, 0.f};
    float bv[8];
#pragma unroll
    for (int e = 0; e < 8; ++e) bv[e] = Cb[(g * 8 + e) * 1024 + col];  // C[f][0][j]
    mfma16(acc, afr0, mk8(bv));
#pragma unroll
    for (int e = 0; e < 8; ++e) bv[e] = Cb[(32 + g * 8 + e) * 1024 + col];
    mfma16(acc, afr1, mk8(bv));
#pragma unroll
    for (int r = 0; r < 4; ++r)
      v0[(p * 64 + m * 16 + g * 4 + r) * 32 + col] = acc[r];
  } else {
#pragma unroll 4
    for (int nt = 0; nt < NTW; ++nt) {
      const int col = nq * NC + (nh * NTW + nt) * 16 + l15;   // ij
      f32x4 acc = {0.f, 0.f, 0.f, 0.f};
      float bv[8];
#pragma unroll
      for (int e = 0; e < 8; ++e) bv[e] = Cb[(g * 8 + e) * 1024 + col];
      mfma16(acc, afr0, mk8(bv));
#pragma unroll
      for (int e = 0; e < 8; ++e) bv[e] = Cb[(32 + g * 8 + e) * 1024 + col];
      mfma16(acc, afr1, mk8(bv));
      u16* mp = mats + (((size_t)p * (S - 1) + (s - 1)) * 64 + m * 16 + g * 4) * 1024 + col;
#pragma unroll
      for (int r = 0; r < 4; ++r) mp[r * 1024] = (u16)f2bf(acc[r]);
    }
  }
}

// ---------------------------------------------------------------------------
// Chain (levels 2,3): v0 -> xM1 xM2 xM3 -> label -> yraw[o][P][b] + BN partials.
// Dense label read from labD. LEVEL2: wave does 4 b's; LEVEL3: 1 b.
// ---------------------------------------------------------------------------
template <int LEVEL>
__global__ __launch_bounds__(256) void k_chain(const float* __restrict__ v0,
                                               const u16* __restrict__ mats,
                                               const float* __restrict__ labD,
                                               float* __restrict__ yraw,
                                               float* __restrict__ sumsN) {
  constexpr int P = (LEVEL == 2) ? 64 : 16;
  constexpr int NB = (LEVEL == 2) ? 4 : 1;   // b's per wave
  __shared__ float lab_s[1024];   // [j][o]
  __shared__ float bnp_s[4][2][32];
  const int t = threadIdx.x, w = t >> 6, lane = t & 63;
  int p, b0;
  if (LEVEL == 2) { p = blockIdx.x >> 2; b0 = (blockIdx.x & 3) * 16 + w * 4; }
  else            { p = blockIdx.x >> 4; b0 = (blockIdx.x & 15) * 4 + w; }
  for (int i = t; i < 1024; i += 256) lab_s[i] = labD[p * 1024 + i];
  __syncthreads();
  const int j = lane & 31;
  float cs = 0.f, cq = 0.f;
#pragma unroll
  for (int bi = 0; bi < NB; ++bi) {
    const int b = b0 + bi;
    float v = v0[(p * 64 + b) * 32 + j];
#pragma unroll
    for (int s1 = 0; s1 < 3; ++s1) {
      const u16* M = mats + (((size_t)p * 3 + s1) * 64 + b) * 1024;
      float acc = 0.f;
#pragma unroll
      for (int i = 0; i < 32; ++i)
        acc += __shfl(v, i, 64) * bfu2f(M[i * 32 + j]);
      v = acc;
    }
    float out = 0.f;
#pragma unroll
    for (int jj = 0; jj < 32; ++jj)
      out += __shfl(v, jj, 64) * lab_s[jj * 32 + j];
    if (lane < 32) {
      yraw[(j * P + p) * 64 + b] = out;
      cs += out;
      cq += out * out;
    }
  }
  if (lane < 32) { bnp_s[w][0][j] = cs; bnp_s[w][1][j] = cq; }
  __syncthreads();
  if (t < 64) {
    const int jj = t & 31, h = t >> 5;
    atomicAdd(&sumsN[2 * jj + h],
              bnp_s[0][h][jj] + bnp_s[1][h][jj] + bnp_s[2][h][jj] + bnp_s[3][h][jj]);
  }
}

// ---------------------------------------------------------------------------
// Final chain (R6 verbatim): 15 site matrices then labelF dot. Wave per b.
// ---------------------------------------------------------------------------
__global__ __launch_bounds__(64) void k_chainF(const float* __restrict__ v0,
                                               const u16* __restrict__ mats,
                                               const float* __restrict__ labelF,
                                               float* __restrict__ out) {
  const int lane = threadIdx.x, b = blockIdx.x, j = lane & 31;
  float v = v0[b * 32 + j];
  for (int s1 = 0; s1 < 15; ++s1) {
    const u16* M = mats + ((size_t)s1 * 64 + b) * 1024;
    float acc = 0.f;
#pragma unroll
    for (int i = 0; i < 32; ++i)
      acc += __shfl(v, i, 64) * bfu2f(M[i * 32 + j]);
    v = acc;
  }
  float r = v * labelF[j * 32];
#pragma unroll
  for (int off = 16; off > 0; off >>= 1) r += __shfl_xor(r, off, 64);
  if (lane == 0) out[b] = r;
}

// ---------------------------------------------------------------------------
extern "C" void kernel_launch(void* const* d_in, const int* in_sizes, int n_in,
                              void* d_out, int out_size, void* d_ws, size_t ws_size,
                              hipStream_t stream) {
  (void)in_sizes; (void)n_in; (void)out_size; (void)ws_size;
  const float* x      = (const float*)d_in[0];
  const float* cores1 = (const float*)d_in[1];
  const float* label1 = (const float*)d_in[2];
  const float* g1     = (const float*)d_in[3];
  const float* b1     = (const float*)d_in[4];
  const float* cores2 = (const float*)d_in[5];
  const float* label2 = (const float*)d_in[6];
  const float* g2     = (const float*)d_in[7];
  const float* b2     = (const float*)d_in[8];
  const float* cores3 = (const float*)d_in[9];
  const float* label3 = (const float*)d_in[10];
  const float* g3     = (const float*)d_in[11];
  const float* b3     = (const float*)d_in[12];
  const float* coresF = (const float*)d_in[13];
  const float* labelF = (const float*)d_in[14];

  char* wsb = (char*)d_ws;
  size_t off = 0;
  auto alloc = [&](size_t bytes) -> char* {
    char* r = wsb + off;
    off += (bytes + 255) & ~(size_t)255;
    return r;
  };
  // phi1 (gather1->level1, 24MB) and mats2 (build2->chain2, 24MB) alias
  char* region0 = alloc(6291456ull * 4);          // 24 MB
  float* phi1  = (float*)region0;                 // [256][4][96][64]
  u16*   mats2 = (u16*)region0;                   // [64][3][64][1024]
  float* y1raw = (float*)alloc(524288ull * 4);    // [32][256][64]
  float* v02   = (float*)alloc(131072ull * 4);    // [64][64][32]
  float* y2raw = (float*)alloc(131072ull * 4);    // [32][64][64]
  float* v03   = (float*)alloc(32768ull * 4);     // [16][64][32]
  u16*   mats3 = (u16*)  alloc(3145728ull * 2);   // [16][3][64][1024]
  float* y3raw = (float*)alloc(32768ull * 4);     // [32][16][64]
  float* v0F   = (float*)alloc(2048ull * 4);      // [64][32]
  u16*   matsF = (u16*)  alloc(983040ull * 2);    // [15][64][1024]
  float* labD2 = (float*)alloc(65536ull * 4);     // [64][1024] dense label2
  float* labD3 = (float*)alloc(16384ull * 4);     // [16][1024] dense label3
  float* sums  = (float*)alloc(192 * 4);          // bn1|bn2|bn3 (sum,sq)x32
  float* sums1 = sums, *sums2 = sums + 64, *sums3 = sums + 128;

  k_gather1<<<768, 256, 0, stream>>>(x, phi1, sums);
  k_level1<<<256, 512, 0, stream>>>(phi1, cores1, label1, y1raw, sums1);
  k_build<2><<<512, 512, 0, stream>>>(y1raw, cores2, mats2, v02, sums1, g1, b1, label2, labD2);
  k_chain<2><<<256, 256, 0, stream>>>(v02, mats2, labD2, y2raw, sums2);
  k_build<3><<<256, 512, 0, stream>>>(y2raw, cores3, mats3, v03, sums2, g2, b2, label3, labD3);
  k_chain<3><<<256, 256, 0, stream>>>(v03, mats3, labD3, y3raw, sums3);
  k_build<0><<<256, 512, 0, stream>>>(y3raw, coresF, matsF, v0F, sums3, g3, b3, nullptr, nullptr);
  k_chainF<<<64, 64, 0, stream>>>(v0F, matsF, labelF, (float*)d_out);
}

// Round 9
// 246.792 us; speedup vs baseline: 1.4690x; 1.4690x over previous
//
#include <hip/hip_runtime.h>

typedef unsigned int u32;
typedef unsigned short u16;
typedef float f32x4 __attribute__((ext_vector_type(4)));
typedef u32 u32x4 __attribute__((ext_vector_type(4)));
typedef short s16x8 __attribute__((ext_vector_type(8)));

__device__ __forceinline__ u32 f2bf(float f) {
  u32 x = __builtin_bit_cast(u32, f);
  return (x + 0x7FFFu + ((x >> 16) & 1u)) >> 16;   // RNE f32 -> bf16 bits
}
__device__ __forceinline__ float bfu2f(u16 u) {
  u32 x = ((u32)u) << 16;
  return __builtin_bit_cast(float, x);
}
__device__ __forceinline__ u32 cvtpk(float lo, float hi) {
  u32 r;
  asm("v_cvt_pk_bf16_f32 %0, %1, %2" : "=v"(r) : "v"(lo), "v"(hi));
  return r;
}
__device__ __forceinline__ u32x4 mk8(const float* v) {
  u32x4 u;
  u.x = cvtpk(v[0], v[1]); u.y = cvtpk(v[2], v[3]);
  u.z = cvtpk(v[4], v[5]); u.w = cvtpk(v[6], v[7]);
  return u;
}
// D = A*B + D, 16x16x32 bf16 builtin. D: n=lane&15, m=(lane>>4)*4+r.
__device__ __forceinline__ void mfma16(f32x4& acc, u32x4 a, u32x4 b) {
  acc = __builtin_amdgcn_mfma_f32_16x16x32_bf16(
      __builtin_bit_cast(s16x8, a), __builtin_bit_cast(s16x8, b), acc, 0, 0, 0);
}

// ---------------------------------------------------------------------------
// K0 (R6-proven verbatim): gather x into phi1[p][s][f][b], f in [0,96): [x,1-x]
// ---------------------------------------------------------------------------
__global__ __launch_bounds__(256) void k_gather1(const float* __restrict__ x,
                                                 float* __restrict__ phi1) {
  __shared__ float tile[64][65];
  const int t = threadIdx.x;
  const int base = blockIdx.x * 64;
  const int lb = t & 63;
  {
    const int flat = base + lb;
    const int c = flat >> 14;
    const int r1 = flat & 16383;
    const int h1 = r1 >> 12;
    const int r2 = r1 & 4095;
    const int w1 = r2 >> 10;
    const int r3 = r2 & 1023;
    const int h2 = r3 >> 5;
    const int w2 = r3 & 31;
    const int xoff = c * 16384 + h1 * 4096 + h2 * 128 + w1 * 32 + w2;
    for (int b = t >> 6; b < 64; b += 4)
      tile[lb][b] = x[b * 49152 + xoff];
  }
  __syncthreads();
  for (int q = t >> 6; q < 64; q += 4) {
    const int flat = base + q;
    const int a = flat / 1536;
    const int rem = flat % 1536;
    const int e = rem / 48, gg = rem % 48;
    const int e1 = e >> 4, e2 = e & 15, g1 = gg >> 4, g2 = gg & 15;
    const int tt = a * 6 + e1 * 3 + g1;
    const int F = tt >> 2, Sx = tt & 3, Pp = e2 * 16 + g2;
    const float val = tile[q][lb];
    const int idx = ((Pp * 4 + Sx) * 96 + F) * 64 + lb;
    phi1[idx] = val;
    phi1[idx + 3072] = 1.0f - val;   // f+48
  }
}

// ---------------------------------------------------------------------------
// K1 (R6-proven BYTE-FROZEN): level-1 fused vector-chain.
// ---------------------------------------------------------------------------
__global__ __launch_bounds__(512) void k_level1(const float* __restrict__ phi1,
                                                const float* __restrict__ cores1,
                                                const float* __restrict__ label1,
                                                float* __restrict__ y1raw) {
  __shared__ float phi_s[96 * 64];          // 24 KB
  __shared__ float v_s[64 * 33];            // 8.4 KB
  __shared__ float red_s[8 * 4 * 16 * 17];  // 34.8 KB
  __shared__ float lab_s[1024];             // 4 KB
  const int p = blockIdx.x, t = threadIdx.x;
  const int w = t >> 6, lane = t & 63, g = lane >> 4, l15 = lane & 15;
  const int jm = w & 1, fq = w >> 1;
  const float* phip = phi1 + p * 24576;
  const float* Cp = cores1 + p * 393216;

  // stage phi(site 0)
  {
    const float4* s4 = (const float4*)phip;
    float4* d4 = (float4*)phi_s;
#pragma unroll
    for (int k = 0; k < 3; ++k) d4[t + k * 512] = s4[t + k * 512];
  }
  __syncthreads();
  // site 0: v[b,j] = sum_f phi[b,f] * C[p,0,f,0,j]
  {
    const int rowj = jm * 16 + l15, colb = fq * 16 + l15;
    f32x4 acc = {0.f, 0.f, 0.f, 0.f};
    const float* A0 = Cp + rowj;
#pragma unroll
    for (int ks = 0; ks < 3; ++ks) {
      float av[8], bv[8];
#pragma unroll
      for (int e = 0; e < 8; ++e) {
        const int f = ks * 32 + g * 8 + e;
        av[e] = A0[f * 1024];
        bv[e] = phi_s[f * 64 + colb];
      }
      mfma16(acc, mk8(av), mk8(bv));
    }
#pragma unroll
    for (int r = 0; r < 4; ++r) v_s[colb * 33 + jm * 16 + g * 4 + r] = acc[r];
  }
  // sites 1..3
  for (int s = 1; s < 4; ++s) {
    __syncthreads();   // v_s complete; phi_s free
    float v8[4][8];
#pragma unroll
    for (int n = 0; n < 4; ++n)
#pragma unroll
      for (int e = 0; e < 8; ++e)
        v8[n][e] = v_s[(n * 16 + l15) * 33 + g * 8 + e];
    {
      const float4* s4 = (const float4*)(phip + s * 6144);
      float4* d4 = (float4*)phi_s;
#pragma unroll
      for (int k = 0; k < 3; ++k) d4[t + k * 512] = s4[t + k * 512];
    }
    // A(f,e) = As[f*1024 + e*32] = C[p][s][fq*24+f][i=g*8+e][j=jm*16+l15]
    const float* As = Cp + s * 98304 + fq * 24576 + g * 256 + jm * 16 + l15;
    float pf[6][8];
#pragma unroll
    for (int fi = 0; fi < 6; ++fi)
#pragma unroll
      for (int e = 0; e < 8; ++e) pf[fi][e] = As[fi * 1024 + e * 32];
    __syncthreads();   // phi ready
    f32x4 acc[4];
#pragma unroll
    for (int n = 0; n < 4; ++n) acc[n] = (f32x4){0.f, 0.f, 0.f, 0.f};
#pragma unroll
    for (int fo = 0; fo < 4; ++fo) {
#pragma unroll
      for (int fi = 0; fi < 6; ++fi) {
        const int f = fo * 6 + fi;
        const u32x4 afr = mk8(pf[fi]);
        if (f + 6 < 24) {
#pragma unroll
          for (int e = 0; e < 8; ++e) pf[fi][e] = As[(f + 6) * 1024 + e * 32];
        }
#pragma unroll
        for (int n = 0; n < 4; ++n) {
          const float phf = phi_s[(fq * 24 + f) * 64 + n * 16 + l15];
          float bv[8];
#pragma unroll
          for (int e = 0; e < 8; ++e) bv[e] = phf * v8[n][e];
          mfma16(acc[n], afr, mk8(bv));
        }
      }
    }
#pragma unroll
    for (int n = 0; n < 4; ++n)
#pragma unroll
      for (int r = 0; r < 4; ++r)
        red_s[((w * 4 + n) * 16 + g * 4 + r) * 17 + l15] = acc[n][r];
    __syncthreads();
    // v[b][j] = sum of 4 fq-partials (waves jj+2*fq)
    for (int i = t; i < 2048; i += 512) {
      const int b = i >> 5, j = i & 31;
      const int n = b >> 4, lb = b & 15, jj = j >> 4, row = j & 15;
      v_s[b * 33 + j] = red_s[(((jj)*4 + n) * 16 + row) * 17 + lb]
                      + red_s[(((jj + 2) * 4 + n) * 16 + row) * 17 + lb]
                      + red_s[(((jj + 4) * 4 + n) * 16 + row) * 17 + lb]
                      + red_s[(((jj + 6) * 4 + n) * 16 + row) * 17 + lb];
    }
  }
  __syncthreads();
  // label contraction: y[b,o] = sum_j v[b,j] * label1[p,o,j,0]
  for (int i = t; i < 1024; i += 512)
    lab_s[(i & 31) * 32 + (i >> 5)] = label1[(p * 1024 + i) * 32];
  __syncthreads();
  {
    const int b = t & 63, og = t >> 6;
    float a[4] = {0.f, 0.f, 0.f, 0.f};
    for (int j = 0; j < 32; ++j) {
      const float vj = v_s[b * 33 + j];
#pragma unroll
      for (int r = 0; r < 4; ++r) a[r] += vj * lab_s[j * 32 + og * 4 + r];
    }
#pragma unroll
    for (int r = 0; r < 4; ++r)
      y1raw[((og * 4 + r) * 256 + p) * 64 + b] = a[r];
  }
}

// ---------------------------------------------------------------------------
// BN partial stats: 256 blocks, (o = bid>>3, chunk c = bid&7). Plain stores,
// no atomics. part[(o*8+c)*2 + {0,1}] = (sum, sumsq) over chunk.
// ---------------------------------------------------------------------------
__global__ __launch_bounds__(256) void k_bnpart(const float* __restrict__ y,
                                                float* __restrict__ part,
                                                int N) {
  __shared__ float rs[256], rq[256];
  const int o = blockIdx.x >> 3, c = blockIdx.x & 7;
  const int CH = N >> 3;
  const float* src = y + o * N + c * CH;
  const int t = threadIdx.x;
  float s = 0.f, q = 0.f;
  for (int i = t; i < CH; i += 256) { const float v = src[i]; s += v; q += v * v; }
  rs[t] = s; rq[t] = q;
  __syncthreads();
  for (int k = 128; k > 0; k >>= 1) {
    if (t < k) { rs[t] += rs[t + k]; rq[t] += rq[t + k]; }
    __syncthreads();
  }
  if (t == 0) {
    part[(o * 8 + c) * 2] = rs[0];
    part[(o * 8 + c) * 2 + 1] = rq[0];
  }
}

// ---------------------------------------------------------------------------
// Build site matrices (levels 2,3, final). R6-proven body; BN scale/shift
// derived in prologue from 8-chunk partials (R7-proven pattern, no atomics).
// ---------------------------------------------------------------------------
template <int LEVEL>
__global__ __launch_bounds__(512) void k_build(const float* __restrict__ yraw,
                                               const float* __restrict__ cores,
                                               u16* __restrict__ mats,
                                               float* __restrict__ v0,
                                               const float* __restrict__ part,
                                               const float* __restrict__ gamma,
                                               const float* __restrict__ beta) {
  constexpr int S = (LEVEL == 0) ? 16 : 4;
  constexpr int NQ = (LEVEL == 2) ? 2 : ((LEVEL == 3) ? 4 : 16);
  constexpr int NC = 1024 / NQ;
  constexpr int NTW = NC / 32;
  constexpr float BN_N = (LEVEL == 2) ? 16384.f : ((LEVEL == 3) ? 4096.f : 1024.f);
  __shared__ float phi_s[64 * 64];
  __shared__ float scsh_s[64];
  const int bid = blockIdx.x;
  const int p = bid / (S * NQ);
  const int rs = bid % (S * NQ);
  const int s = rs / NQ, nq = rs % NQ;
  if (s == 0 && nq != 0) return;   // block-uniform early exit
  const int t = threadIdx.x;
  const int w = t >> 6, lane = t & 63;
  const int g = lane >> 4, l15 = lane & 15;
  if (t < 32) {
    float sm = 0.f, sq = 0.f;
#pragma unroll
    for (int c = 0; c < 8; ++c) {
      sm += part[(t * 8 + c) * 2];
      sq += part[(t * 8 + c) * 2 + 1];
    }
    const float mean = sm / BN_N;
    const float var = sq / BN_N - mean * mean;
    const float sc = gamma[t] * rsqrtf(fmaxf(var, 0.f) + 1e-5f);
    scsh_s[2 * t] = sc;
    scsh_s[2 * t + 1] = beta[t] - mean * sc;
  }
  __syncthreads();
  for (int i = t; i < 2048; i += 512) {
    const int f = i >> 6, b = i & 63;
    int src;
    if (LEVEL == 2) {
      const int u = (s >> 1) * 8 + (p >> 3), vv = (s & 1) * 8 + (p & 7);
      src = (f * 256 + u * 16 + vv) * 64 + b;
    } else if (LEVEL == 3) {
      const int u = (s >> 1) * 4 + (p >> 2), vv = (s & 1) * 4 + (p & 3);
      src = (f * 64 + u * 8 + vv) * 64 + b;
    } else {
      src = (f * 16 + s) * 64 + b;
    }
    const float val = fmaf(yraw[src], scsh_s[2 * f], scsh_s[2 * f + 1]);
    phi_s[f * 64 + b] = val;
    phi_s[(f + 32) * 64 + b] = 1.0f - val;
  }
  __syncthreads();
  const float* Cb = cores + (p * S + s) * 65536;
  const int m = w & 3, nh = w >> 2;
  const int rowb = m * 16 + l15;
  float av[8];
#pragma unroll
  for (int e = 0; e < 8; ++e) av[e] = phi_s[(g * 8 + e) * 64 + rowb];
  const u32x4 afr0 = mk8(av);
#pragma unroll
  for (int e = 0; e < 8; ++e) av[e] = phi_s[(32 + g * 8 + e) * 64 + rowb];
  const u32x4 afr1 = mk8(av);
  if (s == 0) {
    const int col = nh * 16 + l15;   // j in [0,32)
    f32x4 acc = {0.f, 0.f, 0.f, 0.f};
    float bv[8];
#pragma unroll
    for (int e = 0; e < 8; ++e) bv[e] = Cb[(g * 8 + e) * 1024 + col];  // C[f][0][j]
    mfma16(acc, afr0, mk8(bv));
#pragma unroll
    for (int e = 0; e < 8; ++e) bv[e] = Cb[(32 + g * 8 + e) * 1024 + col];
    mfma16(acc, afr1, mk8(bv));
#pragma unroll
    for (int r = 0; r < 4; ++r)
      v0[(p * 64 + m * 16 + g * 4 + r) * 32 + col] = acc[r];
  } else {
#pragma unroll 4
    for (int nt = 0; nt < NTW; ++nt) {
      const int col = nq * NC + (nh * NTW + nt) * 16 + l15;   // ij
      f32x4 acc = {0.f, 0.f, 0.f, 0.f};
      float bv[8];
#pragma unroll
      for (int e = 0; e < 8; ++e) bv[e] = Cb[(g * 8 + e) * 1024 + col];
      mfma16(acc, afr0, mk8(bv));
#pragma unroll
      for (int e = 0; e < 8; ++e) bv[e] = Cb[(32 + g * 8 + e) * 1024 + col];
      mfma16(acc, afr1, mk8(bv));
      u16* mp = mats + (((size_t)p * (S - 1) + (s - 1)) * 64 + m * 16 + g * 4) * 1024 + col;
#pragma unroll
      for (int r = 0; r < 4; ++r) mp[r * 1024] = (u16)f2bf(acc[r]);
    }
  }
}

// ---------------------------------------------------------------------------
// Chain (levels 2,3) (R6-proven verbatim): v0 -> xM1 xM2 xM3 -> label -> yraw.
// ---------------------------------------------------------------------------
template <int LEVEL>
__global__ __launch_bounds__(256) void k_chain(const float* __restrict__ v0,
                                               const u16* __restrict__ mats,
                                               const float* __restrict__ label,
                                               float* __restrict__ yraw) {
  constexpr int P = (LEVEL == 2) ? 64 : 16;
  constexpr int NB = (LEVEL == 2) ? 4 : 1;   // b's per wave
  __shared__ float lab_s[1024];   // [j][o]
  const int t = threadIdx.x, w = t >> 6, lane = t & 63;
  int p, b0;
  if (LEVEL == 2) { p = blockIdx.x >> 2; b0 = (blockIdx.x & 3) * 16 + w * 4; }
  else            { p = blockIdx.x >> 4; b0 = (blockIdx.x & 15) * 4 + w; }
  for (int i = t; i < 1024; i += 256)
    lab_s[(i & 31) * 32 + (i >> 5)] = label[(p * 1024 + i) * 32];
  __syncthreads();
  const int j = lane & 31;
#pragma unroll
  for (int bi = 0; bi < NB; ++bi) {
    const int b = b0 + bi;
    float v = v0[(p * 64 + b) * 32 + j];
#pragma unroll
    for (int s1 = 0; s1 < 3; ++s1) {
      const u16* M = mats + (((size_t)p * 3 + s1) * 64 + b) * 1024;
      float acc = 0.f;
#pragma unroll
      for (int i = 0; i < 32; ++i)
        acc += __shfl(v, i, 64) * bfu2f(M[i * 32 + j]);
      v = acc;
    }
    float out = 0.f;
#pragma unroll
    for (int jj = 0; jj < 32; ++jj)
      out += __shfl(v, jj, 64) * lab_s[jj * 32 + j];
    if (lane < 32) yraw[(j * P + p) * 64 + b] = out;
  }
}

// ---------------------------------------------------------------------------
// Final chain: stage all 15 site matrices to LDS upfront (one latency round),
// then 15 shuffle-dot steps from LDS. One wave per block (per b).
// ---------------------------------------------------------------------------
__global__ __launch_bounds__(64) void k_chainF(const float* __restrict__ v0,
                                               const u16* __restrict__ mats,
                                               const float* __restrict__ labelF,
                                               float* __restrict__ out) {
  __shared__ u16 m_s[15 * 1024];   // 30 KB
  const int lane = threadIdx.x, b = blockIdx.x, j = lane & 31;
  {
    uint4* dst = (uint4*)m_s;
#pragma unroll
    for (int s1 = 0; s1 < 15; ++s1) {
      const uint4* src = (const uint4*)(mats + ((size_t)s1 * 64 + b) * 1024);
      dst[s1 * 128 + lane] = src[lane];
      dst[s1 * 128 + 64 + lane] = src[64 + lane];
    }
  }
  float v = v0[b * 32 + j];
  __syncthreads();
  for (int s1 = 0; s1 < 15; ++s1) {
    float acc = 0.f;
#pragma unroll
    for (int i = 0; i < 32; ++i)
      acc += __shfl(v, i, 64) * bfu2f(m_s[s1 * 1024 + i * 32 + j]);
    v = acc;
  }
  float r = v * labelF[j * 32];
#pragma unroll
  for (int off = 16; off > 0; off >>= 1) r += __shfl_xor(r, off, 64);
  if (lane == 0) out[b] = r;
}

// ---------------------------------------------------------------------------
extern "C" void kernel_launch(void* const* d_in, const int* in_sizes, int n_in,
                              void* d_out, int out_size, void* d_ws, size_t ws_size,
                              hipStream_t stream) {
  (void)in_sizes; (void)n_in; (void)out_size; (void)ws_size;
  const float* x      = (const float*)d_in[0];
  const float* cores1 = (const float*)d_in[1];
  const float* label1 = (const float*)d_in[2];
  const float* g1     = (const float*)d_in[3];
  const float* b1     = (const float*)d_in[4];
  const float* cores2 = (const float*)d_in[5];
  const float* label2 = (const float*)d_in[6];
  const float* g2     = (const float*)d_in[7];
  const float* b2     = (const float*)d_in[8];
  const float* cores3 = (const float*)d_in[9];
  const float* label3 = (const float*)d_in[10];
  const float* g3     = (const float*)d_in[11];
  const float* b3     = (const float*)d_in[12];
  const float* coresF = (const float*)d_in[13];
  const float* labelF = (const float*)d_in[14];

  char* wsb = (char*)d_ws;
  size_t off = 0;
  auto alloc = [&](size_t bytes) -> char* {
    char* r = wsb + off;
    off += (bytes + 255) & ~(size_t)255;
    return r;
  };
  // phi1 (gather1->level1, 24MB) and mats2 (build2->chain2, 24MB) alias
  char* region0 = alloc(6291456ull * 4);          // 24 MB
  float* phi1  = (float*)region0;                 // [256][4][96][64]
  u16*   mats2 = (u16*)region0;                   // [64][3][64][1024]
  float* y1raw = (float*)alloc(524288ull * 4);    // [32][256][64]
  float* v02   = (float*)alloc(131072ull * 4);    // [64][64][32]
  float* y2raw = (float*)alloc(131072ull * 4);    // [32][64][64]
  float* v03   = (float*)alloc(32768ull * 4);     // [16][64][32]
  u16*   mats3 = (u16*)  alloc(3145728ull * 2);   // [16][3][64][1024]
  float* y3raw = (float*)alloc(32768ull * 4);     // [32][16][64]
  float* v0F   = (float*)alloc(2048ull * 4);      // [64][32]
  u16*   matsF = (u16*)  alloc(983040ull * 2);    // [15][64][1024]
  float* part1 = (float*)alloc(512 * 4);          // [32][8][2]
  float* part2 = (float*)alloc(512 * 4);
  float* part3 = (float*)alloc(512 * 4);

  k_gather1<<<768, 256, 0, stream>>>(x, phi1);
  // DIAGNOSTIC: k_level1 launched twice (idempotent). dur delta vs R6 ~= T(k_level1).
  k_level1<<<256, 512, 0, stream>>>(phi1, cores1, label1, y1raw);
  k_level1<<<256, 512, 0, stream>>>(phi1, cores1, label1, y1raw);
  k_bnpart<<<256, 256, 0, stream>>>(y1raw, part1, 16384);
  k_build<2><<<512, 512, 0, stream>>>(y1raw, cores2, mats2, v02, part1, g1, b1);
  k_chain<2><<<256, 256, 0, stream>>>(v02, mats2, label2, y2raw);
  k_bnpart<<<256, 256, 0, stream>>>(y2raw, part2, 4096);
  k_build<3><<<256, 512, 0, stream>>>(y2raw, cores3, mats3, v03, part2, g2, b2);
  k_chain<3><<<256, 256, 0, stream>>>(v03, mats3, label3, y3raw);
  k_bnpart<<<256, 256, 0, stream>>>(y3raw, part3, 1024);
  k_build<0><<<256, 512, 0, stream>>>(y3raw, coresF, matsF, v0F, part3, g3, b3);
  k_chainF<<<64, 64, 0, stream>>>(v0F, matsF, labelF, (float*)d_out);
}

// Round 10
// 180.711 us; speedup vs baseline: 2.0062x; 1.3657x over previous
//
#include <hip/hip_runtime.h>

typedef unsigned int u32;
typedef unsigned short u16;
typedef float f32x4 __attribute__((ext_vector_type(4)));
typedef u32 u32x4 __attribute__((ext_vector_type(4)));
typedef short s16x8 __attribute__((ext_vector_type(8)));

__device__ __forceinline__ u32 f2bf(float f) {
  u32 x = __builtin_bit_cast(u32, f);
  return (x + 0x7FFFu + ((x >> 16) & 1u)) >> 16;   // RNE f32 -> bf16 bits
}
__device__ __forceinline__ float bfu2f(u16 u) {
  u32 x = ((u32)u) << 16;
  return __builtin_bit_cast(float, x);
}
__device__ __forceinline__ u32 cvtpk(float lo, float hi) {
  u32 r;
  asm("v_cvt_pk_bf16_f32 %0, %1, %2" : "=v"(r) : "v"(lo), "v"(hi));
  return r;
}
__device__ __forceinline__ u32x4 mk8(const float* v) {
  u32x4 u;
  u.x = cvtpk(v[0], v[1]); u.y = cvtpk(v[2], v[3]);
  u.z = cvtpk(v[4], v[5]); u.w = cvtpk(v[6], v[7]);
  return u;
}
// D = A*B + D, 16x16x32 bf16 builtin. D: n=lane&15, m=(lane>>4)*4+r.
__device__ __forceinline__ void mfma16(f32x4& acc, u32x4 a, u32x4 b) {
  acc = __builtin_amdgcn_mfma_f32_16x16x32_bf16(
      __builtin_bit_cast(s16x8, a), __builtin_bit_cast(s16x8, b), acc, 0, 0, 0);
}

// ---------------------------------------------------------------------------
// K0 (R6-proven verbatim): gather x into phi1[p][s][f][b], f in [0,96): [x,1-x]
// ---------------------------------------------------------------------------
__global__ __launch_bounds__(256) void k_gather1(const float* __restrict__ x,
                                                 float* __restrict__ phi1) {
  __shared__ float tile[64][65];
  const int t = threadIdx.x;
  const int base = blockIdx.x * 64;
  const int lb = t & 63;
  {
    const int flat = base + lb;
    const int c = flat >> 14;
    const int r1 = flat & 16383;
    const int h1 = r1 >> 12;
    const int r2 = r1 & 4095;
    const int w1 = r2 >> 10;
    const int r3 = r2 & 1023;
    const int h2 = r3 >> 5;
    const int w2 = r3 & 31;
    const int xoff = c * 16384 + h1 * 4096 + h2 * 128 + w1 * 32 + w2;
    for (int b = t >> 6; b < 64; b += 4)
      tile[lb][b] = x[b * 49152 + xoff];
  }
  __syncthreads();
  for (int q = t >> 6; q < 64; q += 4) {
    const int flat = base + q;
    const int a = flat / 1536;
    const int rem = flat % 1536;
    const int e = rem / 48, gg = rem % 48;
    const int e1 = e >> 4, e2 = e & 15, g1 = gg >> 4, g2 = gg & 15;
    const int tt = a * 6 + e1 * 3 + g1;
    const int F = tt >> 2, Sx = tt & 3, Pp = e2 * 16 + g2;
    const float val = tile[q][lb];
    const int idx = ((Pp * 4 + Sx) * 96 + F) * 64 + lb;
    phi1[idx] = val;
    phi1[idx + 3072] = 1.0f - val;   // f+48
  }
}

// ---------------------------------------------------------------------------
// K1 (R6-proven BYTE-FROZEN): level-1 fused vector-chain.
// ---------------------------------------------------------------------------
__global__ __launch_bounds__(512) void k_level1(const float* __restrict__ phi1,
                                                const float* __restrict__ cores1,
                                                const float* __restrict__ label1,
                                                float* __restrict__ y1raw) {
  __shared__ float phi_s[96 * 64];          // 24 KB
  __shared__ float v_s[64 * 33];            // 8.4 KB
  __shared__ float red_s[8 * 4 * 16 * 17];  // 34.8 KB
  __shared__ float lab_s[1024];             // 4 KB
  const int p = blockIdx.x, t = threadIdx.x;
  const int w = t >> 6, lane = t & 63, g = lane >> 4, l15 = lane & 15;
  const int jm = w & 1, fq = w >> 1;
  const float* phip = phi1 + p * 24576;
  const float* Cp = cores1 + p * 393216;

  // stage phi(site 0)
  {
    const float4* s4 = (const float4*)phip;
    float4* d4 = (float4*)phi_s;
#pragma unroll
    for (int k = 0; k < 3; ++k) d4[t + k * 512] = s4[t + k * 512];
  }
  __syncthreads();
  // site 0: v[b,j] = sum_f phi[b,f] * C[p,0,f,0,j]
  {
    const int rowj = jm * 16 + l15, colb = fq * 16 + l15;
    f32x4 acc = {0.f, 0.f, 0.f, 0.f};
    const float* A0 = Cp + rowj;
#pragma unroll
    for (int ks = 0; ks < 3; ++ks) {
      float av[8], bv[8];
#pragma unroll
      for (int e = 0; e < 8; ++e) {
        const int f = ks * 32 + g * 8 + e;
        av[e] = A0[f * 1024];
        bv[e] = phi_s[f * 64 + colb];
      }
      mfma16(acc, mk8(av), mk8(bv));
    }
#pragma unroll
    for (int r = 0; r < 4; ++r) v_s[colb * 33 + jm * 16 + g * 4 + r] = acc[r];
  }
  // sites 1..3
  for (int s = 1; s < 4; ++s) {
    __syncthreads();   // v_s complete; phi_s free
    float v8[4][8];
#pragma unroll
    for (int n = 0; n < 4; ++n)
#pragma unroll
      for (int e = 0; e < 8; ++e)
        v8[n][e] = v_s[(n * 16 + l15) * 33 + g * 8 + e];
    {
      const float4* s4 = (const float4*)(phip + s * 6144);
      float4* d4 = (float4*)phi_s;
#pragma unroll
      for (int k = 0; k < 3; ++k) d4[t + k * 512] = s4[t + k * 512];
    }
    // A(f,e) = As[f*1024 + e*32] = C[p][s][fq*24+f][i=g*8+e][j=jm*16+l15]
    const float* As = Cp + s * 98304 + fq * 24576 + g * 256 + jm * 16 + l15;
    float pf[6][8];
#pragma unroll
    for (int fi = 0; fi < 6; ++fi)
#pragma unroll
      for (int e = 0; e < 8; ++e) pf[fi][e] = As[fi * 1024 + e * 32];
    __syncthreads();   // phi ready
    f32x4 acc[4];
#pragma unroll
    for (int n = 0; n < 4; ++n) acc[n] = (f32x4){0.f, 0.f, 0.f, 0.f};
#pragma unroll
    for (int fo = 0; fo < 4; ++fo) {
#pragma unroll
      for (int fi = 0; fi < 6; ++fi) {
        const int f = fo * 6 + fi;
        const u32x4 afr = mk8(pf[fi]);
        if (f + 6 < 24) {
#pragma unroll
          for (int e = 0; e < 8; ++e) pf[fi][e] = As[(f + 6) * 1024 + e * 32];
        }
#pragma unroll
        for (int n = 0; n < 4; ++n) {
          const float phf = phi_s[(fq * 24 + f) * 64 + n * 16 + l15];
          float bv[8];
#pragma unroll
          for (int e = 0; e < 8; ++e) bv[e] = phf * v8[n][e];
          mfma16(acc[n], afr, mk8(bv));
        }
      }
    }
#pragma unroll
    for (int n = 0; n < 4; ++n)
#pragma unroll
      for (int r = 0; r < 4; ++r)
        red_s[((w * 4 + n) * 16 + g * 4 + r) * 17 + l15] = acc[n][r];
    __syncthreads();
    // v[b][j] = sum of 4 fq-partials (waves jj+2*fq)
    for (int i = t; i < 2048; i += 512) {
      const int b = i >> 5, j = i & 31;
      const int n = b >> 4, lb = b & 15, jj = j >> 4, row = j & 15;
      v_s[b * 33 + j] = red_s[(((jj)*4 + n) * 16 + row) * 17 + lb]
                      + red_s[(((jj + 2) * 4 + n) * 16 + row) * 17 + lb]
                      + red_s[(((jj + 4) * 4 + n) * 16 + row) * 17 + lb]
                      + red_s[(((jj + 6) * 4 + n) * 16 + row) * 17 + lb];
    }
  }
  __syncthreads();
  // label contraction: y[b,o] = sum_j v[b,j] * label1[p,o,j,0]
  for (int i = t; i < 1024; i += 512)
    lab_s[(i & 31) * 32 + (i >> 5)] = label1[(p * 1024 + i) * 32];
  __syncthreads();
  {
    const int b = t & 63, og = t >> 6;
    float a[4] = {0.f, 0.f, 0.f, 0.f};
    for (int j = 0; j < 32; ++j) {
      const float vj = v_s[b * 33 + j];
#pragma unroll
      for (int r = 0; r < 4; ++r) a[r] += vj * lab_s[j * 32 + og * 4 + r];
    }
#pragma unroll
    for (int r = 0; r < 4; ++r)
      y1raw[((og * 4 + r) * 256 + p) * 64 + b] = a[r];
  }
}

// ---------------------------------------------------------------------------
// BN partial stats (R9-proven): 256 blocks, (o = bid>>3, chunk c = bid&7).
// Plain stores, no atomics.
// ---------------------------------------------------------------------------
__global__ __launch_bounds__(256) void k_bnpart(const float* __restrict__ y,
                                                float* __restrict__ part,
                                                int N) {
  __shared__ float rs[256], rq[256];
  const int o = blockIdx.x >> 3, c = blockIdx.x & 7;
  const int CH = N >> 3;
  const float* src = y + o * N + c * CH;
  const int t = threadIdx.x;
  float s = 0.f, q = 0.f;
  for (int i = t; i < CH; i += 256) { const float v = src[i]; s += v; q += v * v; }
  rs[t] = s; rq[t] = q;
  __syncthreads();
  for (int k = 128; k > 0; k >>= 1) {
    if (t < k) { rs[t] += rs[t + k]; rq[t] += rq[t + k]; }
    __syncthreads();
  }
  if (t == 0) {
    part[(o * 8 + c) * 2] = rs[0];
    part[(o * 8 + c) * 2 + 1] = rq[0];
  }
}

// ---------------------------------------------------------------------------
// Build site matrices (R9-proven): BN scale/shift from 8-chunk partials.
// ---------------------------------------------------------------------------
template <int LEVEL>
__global__ __launch_bounds__(512) void k_build(const float* __restrict__ yraw,
                                               const float* __restrict__ cores,
                                               u16* __restrict__ mats,
                                               float* __restrict__ v0,
                                               const float* __restrict__ part,
                                               const float* __restrict__ gamma,
                                               const float* __restrict__ beta) {
  constexpr int S = (LEVEL == 0) ? 16 : 4;
  constexpr int NQ = (LEVEL == 2) ? 2 : ((LEVEL == 3) ? 4 : 16);
  constexpr int NC = 1024 / NQ;
  constexpr int NTW = NC / 32;
  constexpr float BN_N = (LEVEL == 2) ? 16384.f : ((LEVEL == 3) ? 4096.f : 1024.f);
  __shared__ float phi_s[64 * 64];
  __shared__ float scsh_s[64];
  const int bid = blockIdx.x;
  const int p = bid / (S * NQ);
  const int rs = bid % (S * NQ);
  const int s = rs / NQ, nq = rs % NQ;
  if (s == 0 && nq != 0) return;   // block-uniform early exit
  const int t = threadIdx.x;
  const int w = t >> 6, lane = t & 63;
  const int g = lane >> 4, l15 = lane & 15;
  if (t < 32) {
    float sm = 0.f, sq = 0.f;
#pragma unroll
    for (int c = 0; c < 8; ++c) {
      sm += part[(t * 8 + c) * 2];
      sq += part[(t * 8 + c) * 2 + 1];
    }
    const float mean = sm / BN_N;
    const float var = sq / BN_N - mean * mean;
    const float sc = gamma[t] * rsqrtf(fmaxf(var, 0.f) + 1e-5f);
    scsh_s[2 * t] = sc;
    scsh_s[2 * t + 1] = beta[t] - mean * sc;
  }
  __syncthreads();
  for (int i = t; i < 2048; i += 512) {
    const int f = i >> 6, b = i & 63;
    int src;
    if (LEVEL == 2) {
      const int u = (s >> 1) * 8 + (p >> 3), vv = (s & 1) * 8 + (p & 7);
      src = (f * 256 + u * 16 + vv) * 64 + b;
    } else if (LEVEL == 3) {
      const int u = (s >> 1) * 4 + (p >> 2), vv = (s & 1) * 4 + (p & 3);
      src = (f * 64 + u * 8 + vv) * 64 + b;
    } else {
      src = (f * 16 + s) * 64 + b;
    }
    const float val = fmaf(yraw[src], scsh_s[2 * f], scsh_s[2 * f + 1]);
    phi_s[f * 64 + b] = val;
    phi_s[(f + 32) * 64 + b] = 1.0f - val;
  }
  __syncthreads();
  const float* Cb = cores + (p * S + s) * 65536;
  const int m = w & 3, nh = w >> 2;
  const int rowb = m * 16 + l15;
  float av[8];
#pragma unroll
  for (int e = 0; e < 8; ++e) av[e] = phi_s[(g * 8 + e) * 64 + rowb];
  const u32x4 afr0 = mk8(av);
#pragma unroll
  for (int e = 0; e < 8; ++e) av[e] = phi_s[(32 + g * 8 + e) * 64 + rowb];
  const u32x4 afr1 = mk8(av);
  if (s == 0) {
    const int col = nh * 16 + l15;   // j in [0,32)
    f32x4 acc = {0.f, 0.f, 0.f, 0.f};
    float bv[8];
#pragma unroll
    for (int e = 0; e < 8; ++e) bv[e] = Cb[(g * 8 + e) * 1024 + col];  // C[f][0][j]
    mfma16(acc, afr0, mk8(bv));
#pragma unroll
    for (int e = 0; e < 8; ++e) bv[e] = Cb[(32 + g * 8 + e) * 1024 + col];
    mfma16(acc, afr1, mk8(bv));
#pragma unroll
    for (int r = 0; r < 4; ++r)
      v0[(p * 64 + m * 16 + g * 4 + r) * 32 + col] = acc[r];
  } else {
#pragma unroll 4
    for (int nt = 0; nt < NTW; ++nt) {
      const int col = nq * NC + (nh * NTW + nt) * 16 + l15;   // ij
      f32x4 acc = {0.f, 0.f, 0.f, 0.f};
      float bv[8];
#pragma unroll
      for (int e = 0; e < 8; ++e) bv[e] = Cb[(g * 8 + e) * 1024 + col];
      mfma16(acc, afr0, mk8(bv));
#pragma unroll
      for (int e = 0; e < 8; ++e) bv[e] = Cb[(32 + g * 8 + e) * 1024 + col];
      mfma16(acc, afr1, mk8(bv));
      u16* mp = mats + (((size_t)p * (S - 1) + (s - 1)) * 64 + m * 16 + g * 4) * 1024 + col;
#pragma unroll
      for (int r = 0; r < 4; ++r) mp[r * 1024] = (u16)f2bf(acc[r]);
    }
  }
}

// ---------------------------------------------------------------------------
// Chain (levels 2,3) (R6-proven verbatim): v0 -> xM1 xM2 xM3 -> label -> yraw.
// ---------------------------------------------------------------------------
template <int LEVEL>
__global__ __launch_bounds__(256) void k_chain(const float* __restrict__ v0,
                                               const u16* __restrict__ mats,
                                               const float* __restrict__ label,
                                               float* __restrict__ yraw) {
  constexpr int P = (LEVEL == 2) ? 64 : 16;
  constexpr int NB = (LEVEL == 2) ? 4 : 1;   // b's per wave
  __shared__ float lab_s[1024];   // [j][o]
  const int t = threadIdx.x, w = t >> 6, lane = t & 63;
  int p, b0;
  if (LEVEL == 2) { p = blockIdx.x >> 2; b0 = (blockIdx.x & 3) * 16 + w * 4; }
  else            { p = blockIdx.x >> 4; b0 = (blockIdx.x & 15) * 4 + w; }
  for (int i = t; i < 1024; i += 256)
    lab_s[(i & 31) * 32 + (i >> 5)] = label[(p * 1024 + i) * 32];
  __syncthreads();
  const int j = lane & 31;
#pragma unroll
  for (int bi = 0; bi < NB; ++bi) {
    const int b = b0 + bi;
    float v = v0[(p * 64 + b) * 32 + j];
#pragma unroll
    for (int s1 = 0; s1 < 3; ++s1) {
      const u16* M = mats + (((size_t)p * 3 + s1) * 64 + b) * 1024;
      float acc = 0.f;
#pragma unroll
      for (int i = 0; i < 32; ++i)
        acc += __shfl(v, i, 64) * bfu2f(M[i * 32 + j]);
      v = acc;
    }
    float out = 0.f;
#pragma unroll
    for (int jj = 0; jj < 32; ++jj)
      out += __shfl(v, jj, 64) * lab_s[jj * 32 + j];
    if (lane < 32) yraw[(j * P + p) * 64 + b] = out;
  }
}

// ---------------------------------------------------------------------------
// Final chain (R9-proven): stage all 15 site matrices to LDS upfront, then
// 15 shuffle-dot steps from LDS. One wave per block (per b).
// ---------------------------------------------------------------------------
__global__ __launch_bounds__(64) void k_chainF(const float* __restrict__ v0,
                                               const u16* __restrict__ mats,
                                               const float* __restrict__ labelF,
                                               float* __restrict__ out) {
  __shared__ u16 m_s[15 * 1024];   // 30 KB
  const int lane = threadIdx.x, b = blockIdx.x, j = lane & 31;
  {
    uint4* dst = (uint4*)m_s;
#pragma unroll
    for (int s1 = 0; s1 < 15; ++s1) {
      const uint4* src = (const uint4*)(mats + ((size_t)s1 * 64 + b) * 1024);
      dst[s1 * 128 + lane] = src[lane];
      dst[s1 * 128 + 64 + lane] = src[64 + lane];
    }
  }
  float v = v0[b * 32 + j];
  __syncthreads();
  for (int s1 = 0; s1 < 15; ++s1) {
    float acc = 0.f;
#pragma unroll
    for (int i = 0; i < 32; ++i)
      acc += __shfl(v, i, 64) * bfu2f(m_s[s1 * 1024 + i * 32 + j]);
    v = acc;
  }
  float r = v * labelF[j * 32];
#pragma unroll
  for (int off = 16; off > 0; off >>= 1) r += __shfl_xor(r, off, 64);
  if (lane == 0) out[b] = r;
}

// ---------------------------------------------------------------------------
extern "C" void kernel_launch(void* const* d_in, const int* in_sizes, int n_in,
                              void* d_out, int out_size, void* d_ws, size_t ws_size,
                              hipStream_t stream) {
  (void)in_sizes; (void)n_in; (void)out_size; (void)ws_size;
  const float* x      = (const float*)d_in[0];
  const float* cores1 = (const float*)d_in[1];
  const float* label1 = (const float*)d_in[2];
  const float* g1     = (const float*)d_in[3];
  const float* b1     = (const float*)d_in[4];
  const float* cores2 = (const float*)d_in[5];
  const float* label2 = (const float*)d_in[6];
  const float* g2     = (const float*)d_in[7];
  const float* b2     = (const float*)d_in[8];
  const float* cores3 = (const float*)d_in[9];
  const float* label3 = (const float*)d_in[10];
  const float* g3     = (const float*)d_in[11];
  const float* b3     = (const float*)d_in[12];
  const float* coresF = (const float*)d_in[13];
  const float* labelF = (const float*)d_in[14];

  char* wsb = (char*)d_ws;
  size_t off = 0;
  auto alloc = [&](size_t bytes) -> char* {
    char* r = wsb + off;
    off += (bytes + 255) & ~(size_t)255;
    return r;
  };
  // phi1 (gather1->level1, 24MB) and mats2 (build2->chain2, 24MB) alias
  char* region0 = alloc(6291456ull * 4);          // 24 MB
  float* phi1  = (float*)region0;                 // [256][4][96][64]
  u16*   mats2 = (u16*)region0;                   // [64][3][64][1024]
  float* y1raw = (float*)alloc(524288ull * 4);    // [32][256][64]
  float* v02   = (float*)alloc(131072ull * 4);    // [64][64][32]
  float* y2raw = (float*)alloc(131072ull * 4);    // [32][64][64]
  float* v03   = (float*)alloc(32768ull * 4);     // [16][64][32]
  u16*   mats3 = (u16*)  alloc(3145728ull * 2);   // [16][3][64][1024]
  float* y3raw = (float*)alloc(32768ull * 4);     // [32][16][64]
  float* v0F   = (float*)alloc(2048ull * 4);      // [64][32]
  u16*   matsF = (u16*)  alloc(983040ull * 2);    // [15][64][1024]
  float* part1 = (float*)alloc(512 * 4);          // [32][8][2]
  float* part2 = (float*)alloc(512 * 4);
  float* part3 = (float*)alloc(512 * 4);

  k_gather1<<<768, 256, 0, stream>>>(x, phi1);
  k_level1<<<256, 512, 0, stream>>>(phi1, cores1, label1, y1raw);
  k_bnpart<<<256, 256, 0, stream>>>(y1raw, part1, 16384);
  k_build<2><<<512, 512, 0, stream>>>(y1raw, cores2, mats2, v02, part1, g1, b1);
  k_chain<2><<<256, 256, 0, stream>>>(v02, mats2, label2, y2raw);
  k_bnpart<<<256, 256, 0, stream>>>(y2raw, part2, 4096);
  k_build<3><<<256, 512, 0, stream>>>(y2raw, cores3, mats3, v03, part2, g2, b2);
  k_chain<3><<<256, 256, 0, stream>>>(v03, mats3, label3, y3raw);
  k_bnpart<<<256, 256, 0, stream>>>(y3raw, part3, 1024);
  k_build<0><<<256, 512, 0, stream>>>(y3raw, coresF, matsF, v0F, part3, g3, b3);
  k_chainF<<<64, 64, 0, stream>>>(v0F, matsF, labelF, (float*)d_out);
}